// Round 24
// baseline (159.410 us; speedup 1.0000x reference)
//
#include <hip/hip_runtime.h>

typedef unsigned short u16;
typedef short bfrag __attribute__((ext_vector_type(8)));   // 8 x bf16 (4 VGPRs)
typedef float facc  __attribute__((ext_vector_type(4)));   // 4 x f32
typedef float f16x  __attribute__((ext_vector_type(16)));  // 16 x f32 (32x32 acc)

__device__ __forceinline__ u16 f2bf(float f){
  union { float f; unsigned u; } v; v.f = f;
  unsigned r = v.u + 0x7fffu + ((v.u >> 16) & 1u);
  return (u16)(r >> 16);
}

__device__ __forceinline__ unsigned cvt_pk_bf16(float lo, float hi){
  unsigned d;
  asm("v_cvt_pk_bf16_f32 %0, %1, %2" : "=v"(d) : "v"(lo), "v"(hi));
  return d;
}

__device__ __forceinline__ void gl_lds16(const void* g, void* l){
  __builtin_amdgcn_global_load_lds(
      (const __attribute__((address_space(1))) unsigned int*)g,
      (__attribute__((address_space(3))) unsigned int*)l,
      16, 0, 0);
}

// ---------------- fused fp32 -> bf16 conversion (3 tensors, 1 launch) ----------
__global__ __launch_bounds__(256) void cvt3_kernel(
    const float* __restrict__ s0, u16* __restrict__ d0, int n0,   // x
    const float* __restrict__ s1, u16* __restrict__ d1, int n1,   // w_in
    const float* __restrict__ s2, u16* __restrict__ d2)           // w_out
{
  int i = (blockIdx.x * 256 + threadIdx.x) * 4;
  const float* src; u16* dst;
  if (i < n0){ src = s0; dst = d0; }
  else if (i < n0 + n1){ src = s1; dst = d1; i -= n0; }
  else { src = s2; dst = d2; i -= n0 + n1; }
  float4 f = *(const float4*)(src + i);
  ushort4 o;
  o.x = f2bf(f.x); o.y = f2bf(f.y); o.z = f2bf(f.z); o.w = f2bf(f.w);
  *(ushort4*)(dst + i) = o;
}

// =======================================================================
// GEMM1: 8-phase 256x256 tile, BK=64, 8 waves, st_16x32 swizzle, counted
// vmcnt pipeline. qkv epilogue (q scaled, v transposed). (R19, verified)
// =======================================================================
__global__ __launch_bounds__(512, 2) void gemm8p_qkv(
    const u16* __restrict__ A, const u16* __restrict__ B,
    const float* __restrict__ bias, u16* __restrict__ qkv)
{
  __shared__ u16 lds[66048];
  const int tid = threadIdx.x, lane = tid & 63;
  const int w = tid >> 6, wm = w >> 2, wn = w & 3;
  const int cl = lane & 15, g8 = (lane >> 4) * 8, r0 = (lane >> 4) * 4;
  constexpr int K = 1024, NT = 16;

  const int bid = blockIdx.x;
  const int chunk = bid & 7, pos = bid >> 3;
  const int mt = (chunk >> 2) * 8 + pos / 3;
  const int nt = (chunk & 3) * 3 + pos % 3;
  const int m0 = mt * 256, n0 = nt * 256;

  facc acc[8][4];
  #pragma unroll
  for (int mi = 0; mi < 8; ++mi)
    #pragma unroll
    for (int ni = 0; ni < 4; ++ni) acc[mi][ni] = (facc){0.f, 0.f, 0.f, 0.f};

  int aoff[4][2], boff[2][2];
  #pragma unroll
  for (int mi2 = 0; mi2 < 4; ++mi2)
    #pragma unroll
    for (int ks = 0; ks < 2; ++ks){
      int r = (2 * mi2 + wm) * 16 + cl;
      int U = r * 128 + (ks * 32 + g8) * 2;
      aoff[mi2][ks] = (U ^ (((U >> 9) & 1) << 5)) >> 1;
    }
  #pragma unroll
  for (int ni2 = 0; ni2 < 2; ++ni2)
    #pragma unroll
    for (int ks = 0; ks < 2; ++ks){
      int rB = (4 * ni2 + wn) * 16 + cl;
      int U = rB * 128 + (ks * 32 + g8) * 2;
      boff[ni2][ks] = (U ^ (((U >> 9) & 1) << 5)) >> 1;
    }

  int srow[2], scol[2];
  #pragma unroll
  for (int c = 0; c < 2; ++c){
    int Bh = c * 8192 + tid * 16;
    int E = Bh ^ (((Bh >> 9) & 1) << 5);
    srow[c] = E >> 7; scol[c] = (E & 127) >> 1;
  }

  auto stageA = [&](int t, int h){
    const int k0 = (t < NT) ? t * 64 : 0;
    const int slot = ((2 * t + h) & 3) * 8192;
    #pragma unroll
    for (int c = 0; c < 2; ++c)
      gl_lds16(A + (size_t)(m0 + h * 128 + srow[c]) * K + k0 + scol[c],
               lds + slot + c * 4096 + w * 512);
  };
  auto stageB = [&](int t, int h){
    const int k0 = (t < NT) ? t * 64 : 0;
    const int slot = 32768 + ((2 * t + h) & 3) * 8192;
    #pragma unroll
    for (int c = 0; c < 2; ++c)
      gl_lds16(B + (size_t)(n0 + h * 128 + srow[c]) * K + k0 + scol[c],
               lds + slot + c * 4096 + w * 512);
  };

  stageA(0, 0); stageB(0, 0); stageA(0, 1); stageB(0, 1); stageA(1, 0); stageB(1, 0);

  bfrag af[4][2], bf[2][2];

  for (int j = 0; j < NT; ++j){
    const int sa0 = ((2 * j) & 3) * 8192,         sa1 = ((2 * j + 1) & 3) * 8192;
    const int sb0 = 32768 + ((2 * j) & 3) * 8192, sb1 = 32768 + ((2 * j + 1) & 3) * 8192;

    stageA(j + 1, 1);
    asm volatile("s_waitcnt vmcnt(8)" ::: "memory");
    __builtin_amdgcn_s_barrier();
    #pragma unroll
    for (int mi2 = 0; mi2 < 4; ++mi2)
      #pragma unroll
      for (int ks = 0; ks < 2; ++ks) af[mi2][ks] = *(const bfrag*)&lds[sa0 + aoff[mi2][ks]];
    #pragma unroll
    for (int ni2 = 0; ni2 < 2; ++ni2)
      #pragma unroll
      for (int ks = 0; ks < 2; ++ks) bf[ni2][ks] = *(const bfrag*)&lds[sb0 + boff[ni2][ks]];
    asm volatile("s_waitcnt lgkmcnt(0)" ::: "memory");
    __builtin_amdgcn_sched_barrier(0);
    __builtin_amdgcn_s_setprio(1);
    #pragma unroll
    for (int mi2 = 0; mi2 < 4; ++mi2)
      #pragma unroll
      for (int ni2 = 0; ni2 < 2; ++ni2)
        #pragma unroll
        for (int ks = 0; ks < 2; ++ks)
          acc[mi2][ni2] = __builtin_amdgcn_mfma_f32_16x16x32_bf16(af[mi2][ks], bf[ni2][ks], acc[mi2][ni2], 0, 0, 0);
    __builtin_amdgcn_s_setprio(0);
    __builtin_amdgcn_s_barrier();

    stageB(j + 1, 1);
    asm volatile("s_waitcnt vmcnt(6)" ::: "memory");
    __builtin_amdgcn_s_barrier();
    #pragma unroll
    for (int ni2 = 0; ni2 < 2; ++ni2)
      #pragma unroll
      for (int ks = 0; ks < 2; ++ks) bf[ni2][ks] = *(const bfrag*)&lds[sb1 + boff[ni2][ks]];
    asm volatile("s_waitcnt lgkmcnt(0)" ::: "memory");
    __builtin_amdgcn_sched_barrier(0);
    __builtin_amdgcn_s_setprio(1);
    #pragma unroll
    for (int mi2 = 0; mi2 < 4; ++mi2)
      #pragma unroll
      for (int ni2 = 0; ni2 < 2; ++ni2)
        #pragma unroll
        for (int ks = 0; ks < 2; ++ks)
          acc[mi2][2 + ni2] = __builtin_amdgcn_mfma_f32_16x16x32_bf16(af[mi2][ks], bf[ni2][ks], acc[mi2][2 + ni2], 0, 0, 0);
    __builtin_amdgcn_s_setprio(0);
    __builtin_amdgcn_s_barrier();

    #pragma unroll
    for (int mi2 = 0; mi2 < 4; ++mi2)
      #pragma unroll
      for (int ks = 0; ks < 2; ++ks) af[mi2][ks] = *(const bfrag*)&lds[sa1 + aoff[mi2][ks]];
    #pragma unroll
    for (int ni2 = 0; ni2 < 2; ++ni2)
      #pragma unroll
      for (int ks = 0; ks < 2; ++ks) bf[ni2][ks] = *(const bfrag*)&lds[sb0 + boff[ni2][ks]];
    stageA(j + 2, 0);
    __builtin_amdgcn_s_barrier();
    asm volatile("s_waitcnt lgkmcnt(0)" ::: "memory");
    __builtin_amdgcn_sched_barrier(0);
    __builtin_amdgcn_s_setprio(1);
    #pragma unroll
    for (int mi2 = 0; mi2 < 4; ++mi2)
      #pragma unroll
      for (int ni2 = 0; ni2 < 2; ++ni2)
        #pragma unroll
        for (int ks = 0; ks < 2; ++ks)
          acc[4 + mi2][ni2] = __builtin_amdgcn_mfma_f32_16x16x32_bf16(af[mi2][ks], bf[ni2][ks], acc[4 + mi2][ni2], 0, 0, 0);
    __builtin_amdgcn_s_setprio(0);
    __builtin_amdgcn_s_barrier();

    #pragma unroll
    for (int ni2 = 0; ni2 < 2; ++ni2)
      #pragma unroll
      for (int ks = 0; ks < 2; ++ks) bf[ni2][ks] = *(const bfrag*)&lds[sb1 + boff[ni2][ks]];
    stageB(j + 2, 0);
    __builtin_amdgcn_s_barrier();
    asm volatile("s_waitcnt lgkmcnt(0)" ::: "memory");
    __builtin_amdgcn_sched_barrier(0);
    __builtin_amdgcn_s_setprio(1);
    #pragma unroll
    for (int mi2 = 0; mi2 < 4; ++mi2)
      #pragma unroll
      for (int ni2 = 0; ni2 < 2; ++ni2)
        #pragma unroll
        for (int ks = 0; ks < 2; ++ks)
          acc[4 + mi2][2 + ni2] = __builtin_amdgcn_mfma_f32_16x16x32_bf16(af[mi2][ks], bf[ni2][ks], acc[4 + mi2][2 + ni2], 0, 0, 0);
    __builtin_amdgcn_s_setprio(0);
    __builtin_amdgcn_s_barrier();
  }
  __syncthreads();

  const int bb = m0 >> 11, s0q = m0 & 2047;
  if (n0 < 2048){
    #pragma unroll
    for (int mi = 0; mi < 8; ++mi){
      const int m = m0 + (2 * mi + wm) * 16 + r0;
      #pragma unroll
      for (int ni = 0; ni < 4; ++ni){
        const int n = n0 + (4 * ni + wn) * 16 + cl;
        const float bv = bias[n];
        const int part = n >> 10, rest = n & 1023;
        const int h = rest >> 6, d = rest & 63;
        #pragma unroll
        for (int jj = 0; jj < 4; ++jj){
          float v = acc[mi][ni][jj] + bv;
          if (part == 0) v *= 0.18033688011112042f;
          const int mm = m + jj;
          qkv[(size_t)part * 4194304 + (size_t)(((mm >> 11) * 16 + h) * 2048 + (mm & 2047)) * 64 + d] = f2bf(v);
        }
      }
    }
  } else {
    u16* tr = lds;                              // [4][64][258]
    const int h0 = (n0 - 2048) >> 6;
    #pragma unroll
    for (int mi = 0; mi < 8; ++mi){
      const int sl = (2 * mi + wm) * 16 + r0;
      #pragma unroll
      for (int ni = 0; ni < 4; ++ni){
        const float bv = bias[n0 + (4 * ni + wn) * 16 + cl];
        const int off = (ni * 64 + wn * 16 + cl) * 258 + sl;
        *(unsigned*)&tr[off]     = cvt_pk_bf16(acc[mi][ni][0] + bv, acc[mi][ni][1] + bv);
        *(unsigned*)&tr[off + 2] = cvt_pk_bf16(acc[mi][ni][2] + bv, acc[mi][ni][3] + bv);
      }
    }
    __syncthreads();
    u16* vt_base = qkv + (size_t)2 * 4194304;
    const int hh = tid >> 7, dd = (tid >> 1) & 63, hf = tid & 1;
    u16* dst = vt_base + ((size_t)((bb * 16 + h0 + hh) * 64 + dd)) * 2048 + s0q + hf * 128;
    const u16* srcr = &tr[(hh * 64 + dd) * 258 + hf * 128];
    #pragma unroll
    for (int k = 0; k < 16; ++k)
      *(uint4*)(dst + k * 8) = *(const uint4*)(srcr + k * 8);
  }
}

// ---------------- 128^2 GEMM (output projection) -------------------------------
__device__ __forceinline__ void stage_tile(const u16* __restrict__ G, u16* lds,
                                           int row0, int k0, int K, int tid){
  #pragma unroll
  for (int c = 0; c < 2; ++c){
    int e = c * 2048 + tid * 8;
    int row = e >> 5, col = e & 31;
    gl_lds16(G + (size_t)(row0 + row) * K + k0 + col, lds + c * 2048 + (tid >> 6) * 512);
  }
}

__global__ __launch_bounds__(256) void gemm_out(
    const u16* __restrict__ A, const u16* __restrict__ B,
    const float* __restrict__ bias, float* __restrict__ Cf,
    int M, int N, int K)
{
  __shared__ u16 smem[16384];
  u16* Ash = smem;
  u16* Bsh = smem + 8192;
  const int tid = threadIdx.x, lane = tid & 63;
  const int w = tid >> 6, wm = w >> 1, wn = w & 1;
  const int cl = lane & 15, g8 = (lane >> 4) * 8;

  const int bid = blockIdx.x;
  const int chunk = bid & 7, pos = bid >> 3;
  const int mt = (chunk >> 1) * 8 + pos / 4;
  const int nt = (chunk & 1) * 4 + pos % 4;
  const int n0 = nt * 128, m0 = mt * 128;

  facc acc[4][4];
  #pragma unroll
  for (int mi = 0; mi < 4; ++mi)
    #pragma unroll
    for (int ni = 0; ni < 4; ++ni)
      acc[mi][ni] = (facc){0.f, 0.f, 0.f, 0.f};

  const int NT = K >> 5;
  stage_tile(A, Ash, m0, 0, K, tid);
  stage_tile(B, Bsh, n0, 0, K, tid);
  __syncthreads();
  int cur = 0;
  for (int kt = 0; kt < NT; ++kt){
    if (kt + 1 < NT){
      stage_tile(A, Ash + (cur ^ 1) * 4096, m0, (kt + 1) << 5, K, tid);
      stage_tile(B, Bsh + (cur ^ 1) * 4096, n0, (kt + 1) << 5, K, tid);
    }
    const u16* As = Ash + cur * 4096; const u16* Bs = Bsh + cur * 4096;
    bfrag af[4], bfr[4];
    #pragma unroll
    for (int mi = 0; mi < 4; ++mi)
      af[mi] = *(const bfrag*)&As[(wm * 64 + mi * 16 + cl) * 32 + g8];
    #pragma unroll
    for (int ni = 0; ni < 4; ++ni)
      bfr[ni] = *(const bfrag*)&Bs[(wn * 64 + ni * 16 + cl) * 32 + g8];
    #pragma unroll
    for (int mi = 0; mi < 4; ++mi)
      #pragma unroll
      for (int ni = 0; ni < 4; ++ni)
        acc[mi][ni] = __builtin_amdgcn_mfma_f32_16x16x32_bf16(af[mi], bfr[ni], acc[mi][ni], 0, 0, 0);
    __syncthreads();
    cur ^= 1;
  }

  const int r0 = (lane >> 4) * 4;
  #pragma unroll
  for (int mi = 0; mi < 4; ++mi){
    const int mbase = m0 + wm * 64 + mi * 16 + r0;
    #pragma unroll
    for (int ni = 0; ni < 4; ++ni){
      const int n = n0 + wn * 64 + ni * 16 + cl;
      const float bv = bias[n];
      #pragma unroll
      for (int j = 0; j < 4; ++j)
        Cf[(size_t)(mbase + j) * N + n] = acc[mi][ni][j] + bv;
    }
  }
}

// ---------------- attention per-stripe body on SHARED loaded frags -------------
// NSUB: 32-wide j-subtiles to process (1 or 2). MASK: mask last sub (qj > il).
template<int NSUB, bool MASK>
__device__ __forceinline__ void stripe_body(
    const bfrag (&kf)[8], const bfrag (&vf)[8],
    int il, int hi, const bfrag (&bq)[4],
    f16x& o0, f16x& o1, float& m_s, float& l_s)
{
  f16x s[NSUB];
  #pragma unroll
  for (int sub = 0; sub < NSUB; ++sub)
    #pragma unroll
    for (int r = 0; r < 16; ++r) s[sub][r] = 0.f;
  __builtin_amdgcn_s_setprio(1);
  #pragma unroll
  for (int kt = 0; kt < 4; ++kt)
    #pragma unroll
    for (int sub = 0; sub < NSUB; ++sub)
      s[sub] = __builtin_amdgcn_mfma_f32_32x32x16_bf16(kf[sub * 4 + kt], bq[kt], s[sub], 0, 0, 0);
  __builtin_amdgcn_s_setprio(0);

  if (MASK){
    #pragma unroll
    for (int r = 0; r < 16; ++r){
      const int qj = (r & 3) + 8 * (r >> 2) + 4 * hi;
      if (qj > il) s[NSUB - 1][r] = -1e30f;
    }
  }

  float tmax = -1e30f;
  #pragma unroll
  for (int sub = 0; sub < NSUB; ++sub){
    float a[8];
    #pragma unroll
    for (int e = 0; e < 8; ++e) a[e] = fmaxf(s[sub][e], s[sub][e + 8]);
    #pragma unroll
    for (int e = 0; e < 4; ++e) a[e] = fmaxf(a[e], a[e + 4]);
    a[0] = fmaxf(fmaxf(a[0], a[2]), fmaxf(a[1], a[3]));
    tmax = fmaxf(tmax, a[0]);
  }
  {
    auto tt = __builtin_amdgcn_permlane32_swap(__float_as_uint(tmax),
                                               __float_as_uint(tmax), false, false);
    tmax = fmaxf(__uint_as_float(tt[0]), __uint_as_float(tt[1]));
  }
  if (__any(tmax - m_s > 8.0f)){                // defer-max (THR=8)
    const float nm = fmaxf(m_s, tmax);
    const float sc = __builtin_amdgcn_exp2f(m_s - nm);
    m_s = nm; l_s *= sc;
    #pragma unroll
    for (int r = 0; r < 16; ++r){
      const float scb = __shfl(sc, (r & 3) + 8 * (r >> 2) + 4 * hi, 64);
      o0[r] *= scb; o1[r] *= scb;
    }
  }

  float rsum = 0.f;
  #pragma unroll
  for (int sub = 0; sub < NSUB; ++sub){
    #pragma unroll
    for (int r = 0; r < 16; ++r)
      s[sub][r] = __builtin_amdgcn_exp2f(s[sub][r] - m_s);
    float a[8];
    #pragma unroll
    for (int e = 0; e < 8; ++e) a[e] = s[sub][e] + s[sub][e + 8];
    #pragma unroll
    for (int e = 0; e < 4; ++e) a[e] = a[e] + a[e + 4];
    rsum += (a[0] + a[2]) + (a[1] + a[3]);
  }
  {
    auto rr = __builtin_amdgcn_permlane32_swap(__float_as_uint(rsum),
                                               __float_as_uint(rsum), false, false);
    rsum = __uint_as_float(rr[0]) + __uint_as_float(rr[1]);
  }
  l_s += rsum;

  #pragma unroll
  for (int sub = 0; sub < NSUB; ++sub)
    #pragma unroll
    for (int half = 0; half < 2; ++half){
      const int q0 = 8 * half;
      unsigned a0 = cvt_pk_bf16(s[sub][q0],     s[sub][q0 + 1]);
      unsigned a1 = cvt_pk_bf16(s[sub][q0 + 2], s[sub][q0 + 3]);
      unsigned b0 = cvt_pk_bf16(s[sub][q0 + 4], s[sub][q0 + 5]);
      unsigned b1 = cvt_pk_bf16(s[sub][q0 + 6], s[sub][q0 + 7]);
      auto r0p = __builtin_amdgcn_permlane32_swap(a0, b0, false, false);
      auto r1p = __builtin_amdgcn_permlane32_swap(a1, b1, false, false);
      union { bfrag f; unsigned u[4]; } pa;
      pa.u[0] = r0p[0]; pa.u[1] = r1p[0]; pa.u[2] = r0p[1]; pa.u[3] = r1p[1];

      __builtin_amdgcn_s_setprio(1);
      o0 = __builtin_amdgcn_mfma_f32_32x32x16_bf16(pa.f, vf[sub * 4 + half * 2 + 0], o0, 0, 0, 0);
      o1 = __builtin_amdgcn_mfma_f32_32x32x16_bf16(pa.f, vf[sub * 4 + half * 2 + 1], o1, 0, 0, 0);
      __builtin_amdgcn_s_setprio(0);
    }
}

__device__ __forceinline__ void load_tile(
    bfrag (&kf)[8], bfrag (&vf)[8],
    const u16* __restrict__ Kt, const u16* __restrict__ VTh, int jt, int il, int hi)
{
  #pragma unroll
  for (int sub = 0; sub < 2; ++sub)
    #pragma unroll
    for (int half = 0; half < 2; ++half){
      const int jcol = jt * 64 + sub * 32 + half * 16 + hi * 8;
      vf[sub * 4 + half * 2 + 0] = *(const bfrag*)(VTh + (size_t)il * 2048 + jcol);
      vf[sub * 4 + half * 2 + 1] = *(const bfrag*)(VTh + (size_t)(32 + il) * 2048 + jcol);
    }
  #pragma unroll
  for (int sub = 0; sub < 2; ++sub)
    #pragma unroll
    for (int kt = 0; kt < 4; ++kt)
      kf[sub * 4 + kt] = *(const bfrag*)(Kt + (size_t)(sub * 32 + il) * 64 + kt * 16 + hi * 8);
}

// ---------------- swapped-role causal flash attention (64 rows/wave) -----------
// Block = 128 thr = 2 waves over the SAME 64 output rows (2 stripes of 32);
// wave w processes j-tiles of parity w; K/V frags loaded ONCE per tile and
// shared by both stripes. T14: next tile's loads issued into the OTHER named
// buffer (A/B) before computing the current one — HBM/L2 latency hides under
// the two stripe bodies. 2-partial merge per stripe (R21-verified machinery).
__global__ __launch_bounds__(128, 2) void attn_kernel(
    const u16* __restrict__ qarr, const u16* __restrict__ karr,
    const u16* __restrict__ vtarr, u16* __restrict__ aout,
    const int* __restrict__ cmask)
{
  __shared__ float cO[64 * 64];                 // wave1 partial O (both stripes)
  __shared__ float cm0[64], cl0[64], cm1[64], cl1[64];
  const int tid = threadIdx.x, lane = tid & 63, w = tid >> 6;
  const int il = lane & 31, hi = lane >> 5;
  const int bh = blockIdx.x;                    // bh -> XCD (K/Q/VT L2-resident)
  const int bi = 31 - (int)blockIdx.y;          // 64-row block, heavy first
  const int i0 = bi * 64;
  const u16* Qh  = karr  + (size_t)bh * 131072; // output rows come from k-proj
  const u16* Kh  = qarr  + (size_t)bh * 131072; // keys are q-proj (pre-scaled)
  const u16* VTh = vtarr + (size_t)bh * 131072; // V transposed [d][s]
  const bool do_mask = (cmask[0] != 0);

  // Q B-frags for both stripes
  bfrag bqL[4], bqH[4];
  #pragma unroll
  for (int kt = 0; kt < 4; ++kt){
    bqL[kt] = *(const bfrag*)(Qh + (size_t)(i0 + il) * 64 + kt * 16 + hi * 8);
    bqH[kt] = *(const bfrag*)(Qh + (size_t)(i0 + 32 + il) * 64 + kt * 16 + hi * 8);
  }

  f16x o0L, o1L, o0H, o1H;
  #pragma unroll
  for (int r = 0; r < 16; ++r){ o0L[r] = 0.f; o1L[r] = 0.f; o0H[r] = 0.f; o1H[r] = 0.f; }
  float mL = -1e30f, lL = 0.f, mH = -1e30f, lH = 0.f;

  const int lim = do_mask ? bi : 32;            // full tiles: jt < lim

  bfrag kfA[8], vfA[8], kfB[8], vfB[8];         // named double buffers (rule #20)
  int jt = w;
  if (jt < lim){
    load_tile(kfA, vfA, Kh + (size_t)jt * 4096, VTh, jt, il, hi);
    while (true){
      const int nx = jt + 2;
      const bool more = nx < lim;
      if (more){
        load_tile(kfB, vfB, Kh + (size_t)nx * 4096, VTh, nx, il, hi);
        __builtin_amdgcn_sched_barrier(0);      // pin prefetch above compute
      }
      stripe_body<2, false>(kfA, vfA, il, hi, bqL, o0L, o1L, mL, lL);
      stripe_body<2, false>(kfA, vfA, il, hi, bqH, o0H, o1H, mH, lH);
      if (!more) break;
      jt = nx;
      const int nx2 = jt + 2;
      const bool more2 = nx2 < lim;
      if (more2){
        load_tile(kfA, vfA, Kh + (size_t)nx2 * 4096, VTh, nx2, il, hi);
        __builtin_amdgcn_sched_barrier(0);
      }
      stripe_body<2, false>(kfB, vfB, il, hi, bqL, o0L, o1L, mL, lL);
      stripe_body<2, false>(kfB, vfB, il, hi, bqH, o0H, o1H, mH, lH);
      if (!more2) break;
      jt = nx2;
    }
  }

  if (do_mask && (bi & 1) == w){                // diagonal tile jt = bi, once
    load_tile(kfA, vfA, Kh + (size_t)bi * 4096, VTh, bi, il, hi);
    stripe_body<1, true>(kfA, vfA, il, hi, bqL, o0L, o1L, mL, lL);  // L: sub0 masked
    stripe_body<2, true>(kfA, vfA, il, hi, bqH, o0H, o1H, mH, lH);  // H: sub1 masked
  }

  // ---- merge the two j-parity partials, per stripe ----
  if (w == 1){
    #pragma unroll
    for (int r = 0; r < 16; ++r){
      const int row = (r & 3) + 8 * (r >> 2) + 4 * hi;
      cO[row * 64 + il]             = o0L[r];
      cO[row * 64 + il + 32]        = o1L[r];
      cO[(32 + row) * 64 + il]      = o0H[r];
      cO[(32 + row) * 64 + il + 32] = o1H[r];
    }
    cm1[il] = mL; cl1[il] = lL; cm1[32 + il] = mH; cl1[32 + il] = lH;
  } else {
    cm0[il] = mL; cl0[il] = lL; cm0[32 + il] = mH; cl0[32 + il] = lH;
  }
  __syncthreads();
  if (w == 0){
    const int bb = bh >> 4, h = bh & 15;
    #pragma unroll
    for (int p = 0; p < 2; ++p){
      #pragma unroll
      for (int r = 0; r < 16; ++r){
        const int rl = (r & 3) + 8 * (r >> 2) + 4 * hi;
        const int sr = p * 32 + rl;
        const float mA = cm0[sr], mB = cm1[sr];
        const float lA = cl0[sr], lB = cl1[sr];
        const float M  = fmaxf(mA, mB);
        const float eA = __builtin_amdgcn_exp2f(mA - M);
        const float eB = __builtin_amdgcn_exp2f(mB - M);
        const float inv = 1.0f / (lA * eA + lB * eB);
        const float ob0 = cO[sr * 64 + il], ob1 = cO[sr * 64 + il + 32];
        const float a0 = (p ? o0H[r] : o0L[r]) * eA + ob0 * eB;
        const float a1 = (p ? o1H[r] : o1L[r]) * eA + ob1 * eB;
        u16* dst = aout + (size_t)(bb * 2048 + i0 + sr) * 1024 + h * 64 + il;
        dst[0]  = f2bf(a0 * inv);
        dst[32] = f2bf(a1 * inv);
      }
    }
  }
}

// ---------------- launch ----------------
extern "C" void kernel_launch(void* const* d_in, const int* in_sizes, int n_in,
                              void* d_out, int out_size, void* d_ws, size_t ws_size,
                              hipStream_t stream)
{
  const float* x     = (const float*)d_in[0];
  const float* w_in  = (const float*)d_in[1];
  const float* b_in  = (const float*)d_in[2];
  const float* w_out = (const float*)d_in[3];
  const float* b_out = (const float*)d_in[4];
  const int*   cmask = (const int*)d_in[5];

  u16* ws     = (u16*)d_ws;
  u16* xb     = ws;                 // 4096x1024
  u16* winb   = ws + 4194304;       // 3072x1024
  u16* woutb  = ws + 7340032;       // 1024x1024
  u16* qs     = ws + 8388608;       // q,k: [2,16,2048,64]; VT: [2,16,64,2048]
  u16* attn_o = ws + 20971520;      // 4096x1024

  cvt3_kernel<<<8192, 256, 0, stream>>>(x, xb, 4194304,
                                        w_in, winb, 3145728,
                                        w_out, woutb);

  gemm8p_qkv<<<192, 512, 0, stream>>>(xb, winb, b_in, qs);

  attn_kernel<<<dim3(32, 32), 128, 0, stream>>>(qs, qs + 4194304, qs + 8388608, attn_o, cmask);

  gemm_out<<<256, 256, 0, stream>>>(attn_o, woutb, b_out, (float*)d_out,
                                    4096, 1024, 1024);
}

// Round 25
// 126.117 us; speedup vs baseline: 1.2640x; 1.2640x over previous
//
#include <hip/hip_runtime.h>

typedef unsigned short u16;
typedef short bfrag __attribute__((ext_vector_type(8)));   // 8 x bf16 (4 VGPRs)
typedef float facc  __attribute__((ext_vector_type(4)));   // 4 x f32
typedef float f16x  __attribute__((ext_vector_type(16)));  // 16 x f32 (32x32 acc)

__device__ __forceinline__ u16 f2bf(float f){
  union { float f; unsigned u; } v; v.f = f;
  unsigned r = v.u + 0x7fffu + ((v.u >> 16) & 1u);
  return (u16)(r >> 16);
}

__device__ __forceinline__ unsigned cvt_pk_bf16(float lo, float hi){
  unsigned d;
  asm("v_cvt_pk_bf16_f32 %0, %1, %2" : "=v"(d) : "v"(lo), "v"(hi));
  return d;
}

__device__ __forceinline__ void gl_lds16(const void* g, void* l){
  __builtin_amdgcn_global_load_lds(
      (const __attribute__((address_space(1))) unsigned int*)g,
      (__attribute__((address_space(3))) unsigned int*)l,
      16, 0, 0);
}

// ---------------- fused fp32 -> bf16 conversion (3 tensors, 1 launch) ----------
__global__ __launch_bounds__(256) void cvt3_kernel(
    const float* __restrict__ s0, u16* __restrict__ d0, int n0,   // x
    const float* __restrict__ s1, u16* __restrict__ d1, int n1,   // w_in
    const float* __restrict__ s2, u16* __restrict__ d2)           // w_out
{
  int i = (blockIdx.x * 256 + threadIdx.x) * 4;
  const float* src; u16* dst;
  if (i < n0){ src = s0; dst = d0; }
  else if (i < n0 + n1){ src = s1; dst = d1; i -= n0; }
  else { src = s2; dst = d2; i -= n0 + n1; }
  float4 f = *(const float4*)(src + i);
  ushort4 o;
  o.x = f2bf(f.x); o.y = f2bf(f.y); o.z = f2bf(f.z); o.w = f2bf(f.w);
  *(ushort4*)(dst + i) = o;
}

// =======================================================================
// GEMM1: 8-phase 256x256 tile, BK=64, 8 waves, st_16x32 swizzle, counted
// vmcnt pipeline. qkv epilogue (q scaled, v transposed). (R19, verified)
// =======================================================================
__global__ __launch_bounds__(512, 2) void gemm8p_qkv(
    const u16* __restrict__ A, const u16* __restrict__ B,
    const float* __restrict__ bias, u16* __restrict__ qkv)
{
  __shared__ u16 lds[66048];
  const int tid = threadIdx.x, lane = tid & 63;
  const int w = tid >> 6, wm = w >> 2, wn = w & 3;
  const int cl = lane & 15, g8 = (lane >> 4) * 8, r0 = (lane >> 4) * 4;
  constexpr int K = 1024, NT = 16;

  const int bid = blockIdx.x;
  const int chunk = bid & 7, pos = bid >> 3;
  const int mt = (chunk >> 2) * 8 + pos / 3;
  const int nt = (chunk & 3) * 3 + pos % 3;
  const int m0 = mt * 256, n0 = nt * 256;

  facc acc[8][4];
  #pragma unroll
  for (int mi = 0; mi < 8; ++mi)
    #pragma unroll
    for (int ni = 0; ni < 4; ++ni) acc[mi][ni] = (facc){0.f, 0.f, 0.f, 0.f};

  int aoff[4][2], boff[2][2];
  #pragma unroll
  for (int mi2 = 0; mi2 < 4; ++mi2)
    #pragma unroll
    for (int ks = 0; ks < 2; ++ks){
      int r = (2 * mi2 + wm) * 16 + cl;
      int U = r * 128 + (ks * 32 + g8) * 2;
      aoff[mi2][ks] = (U ^ (((U >> 9) & 1) << 5)) >> 1;
    }
  #pragma unroll
  for (int ni2 = 0; ni2 < 2; ++ni2)
    #pragma unroll
    for (int ks = 0; ks < 2; ++ks){
      int rB = (4 * ni2 + wn) * 16 + cl;
      int U = rB * 128 + (ks * 32 + g8) * 2;
      boff[ni2][ks] = (U ^ (((U >> 9) & 1) << 5)) >> 1;
    }

  int srow[2], scol[2];
  #pragma unroll
  for (int c = 0; c < 2; ++c){
    int Bh = c * 8192 + tid * 16;
    int E = Bh ^ (((Bh >> 9) & 1) << 5);
    srow[c] = E >> 7; scol[c] = (E & 127) >> 1;
  }

  auto stageA = [&](int t, int h){
    const int k0 = (t < NT) ? t * 64 : 0;
    const int slot = ((2 * t + h) & 3) * 8192;
    #pragma unroll
    for (int c = 0; c < 2; ++c)
      gl_lds16(A + (size_t)(m0 + h * 128 + srow[c]) * K + k0 + scol[c],
               lds + slot + c * 4096 + w * 512);
  };
  auto stageB = [&](int t, int h){
    const int k0 = (t < NT) ? t * 64 : 0;
    const int slot = 32768 + ((2 * t + h) & 3) * 8192;
    #pragma unroll
    for (int c = 0; c < 2; ++c)
      gl_lds16(B + (size_t)(n0 + h * 128 + srow[c]) * K + k0 + scol[c],
               lds + slot + c * 4096 + w * 512);
  };

  stageA(0, 0); stageB(0, 0); stageA(0, 1); stageB(0, 1); stageA(1, 0); stageB(1, 0);

  bfrag af[4][2], bf[2][2];

  for (int j = 0; j < NT; ++j){
    const int sa0 = ((2 * j) & 3) * 8192,         sa1 = ((2 * j + 1) & 3) * 8192;
    const int sb0 = 32768 + ((2 * j) & 3) * 8192, sb1 = 32768 + ((2 * j + 1) & 3) * 8192;

    stageA(j + 1, 1);
    asm volatile("s_waitcnt vmcnt(8)" ::: "memory");
    __builtin_amdgcn_s_barrier();
    #pragma unroll
    for (int mi2 = 0; mi2 < 4; ++mi2)
      #pragma unroll
      for (int ks = 0; ks < 2; ++ks) af[mi2][ks] = *(const bfrag*)&lds[sa0 + aoff[mi2][ks]];
    #pragma unroll
    for (int ni2 = 0; ni2 < 2; ++ni2)
      #pragma unroll
      for (int ks = 0; ks < 2; ++ks) bf[ni2][ks] = *(const bfrag*)&lds[sb0 + boff[ni2][ks]];
    asm volatile("s_waitcnt lgkmcnt(0)" ::: "memory");
    __builtin_amdgcn_sched_barrier(0);
    __builtin_amdgcn_s_setprio(1);
    #pragma unroll
    for (int mi2 = 0; mi2 < 4; ++mi2)
      #pragma unroll
      for (int ni2 = 0; ni2 < 2; ++ni2)
        #pragma unroll
        for (int ks = 0; ks < 2; ++ks)
          acc[mi2][ni2] = __builtin_amdgcn_mfma_f32_16x16x32_bf16(af[mi2][ks], bf[ni2][ks], acc[mi2][ni2], 0, 0, 0);
    __builtin_amdgcn_s_setprio(0);
    __builtin_amdgcn_s_barrier();

    stageB(j + 1, 1);
    asm volatile("s_waitcnt vmcnt(6)" ::: "memory");
    __builtin_amdgcn_s_barrier();
    #pragma unroll
    for (int ni2 = 0; ni2 < 2; ++ni2)
      #pragma unroll
      for (int ks = 0; ks < 2; ++ks) bf[ni2][ks] = *(const bfrag*)&lds[sb1 + boff[ni2][ks]];
    asm volatile("s_waitcnt lgkmcnt(0)" ::: "memory");
    __builtin_amdgcn_sched_barrier(0);
    __builtin_amdgcn_s_setprio(1);
    #pragma unroll
    for (int mi2 = 0; mi2 < 4; ++mi2)
      #pragma unroll
      for (int ni2 = 0; ni2 < 2; ++ni2)
        #pragma unroll
        for (int ks = 0; ks < 2; ++ks)
          acc[mi2][2 + ni2] = __builtin_amdgcn_mfma_f32_16x16x32_bf16(af[mi2][ks], bf[ni2][ks], acc[mi2][2 + ni2], 0, 0, 0);
    __builtin_amdgcn_s_setprio(0);
    __builtin_amdgcn_s_barrier();

    #pragma unroll
    for (int mi2 = 0; mi2 < 4; ++mi2)
      #pragma unroll
      for (int ks = 0; ks < 2; ++ks) af[mi2][ks] = *(const bfrag*)&lds[sa1 + aoff[mi2][ks]];
    #pragma unroll
    for (int ni2 = 0; ni2 < 2; ++ni2)
      #pragma unroll
      for (int ks = 0; ks < 2; ++ks) bf[ni2][ks] = *(const bfrag*)&lds[sb0 + boff[ni2][ks]];
    stageA(j + 2, 0);
    __builtin_amdgcn_s_barrier();
    asm volatile("s_waitcnt lgkmcnt(0)" ::: "memory");
    __builtin_amdgcn_sched_barrier(0);
    __builtin_amdgcn_s_setprio(1);
    #pragma unroll
    for (int mi2 = 0; mi2 < 4; ++mi2)
      #pragma unroll
      for (int ni2 = 0; ni2 < 2; ++ni2)
        #pragma unroll
        for (int ks = 0; ks < 2; ++ks)
          acc[4 + mi2][ni2] = __builtin_amdgcn_mfma_f32_16x16x32_bf16(af[mi2][ks], bf[ni2][ks], acc[4 + mi2][ni2], 0, 0, 0);
    __builtin_amdgcn_s_setprio(0);
    __builtin_amdgcn_s_barrier();

    #pragma unroll
    for (int ni2 = 0; ni2 < 2; ++ni2)
      #pragma unroll
      for (int ks = 0; ks < 2; ++ks) bf[ni2][ks] = *(const bfrag*)&lds[sb1 + boff[ni2][ks]];
    stageB(j + 2, 0);
    __builtin_amdgcn_s_barrier();
    asm volatile("s_waitcnt lgkmcnt(0)" ::: "memory");
    __builtin_amdgcn_sched_barrier(0);
    __builtin_amdgcn_s_setprio(1);
    #pragma unroll
    for (int mi2 = 0; mi2 < 4; ++mi2)
      #pragma unroll
      for (int ni2 = 0; ni2 < 2; ++ni2)
        #pragma unroll
        for (int ks = 0; ks < 2; ++ks)
          acc[4 + mi2][2 + ni2] = __builtin_amdgcn_mfma_f32_16x16x32_bf16(af[mi2][ks], bf[ni2][ks], acc[4 + mi2][2 + ni2], 0, 0, 0);
    __builtin_amdgcn_s_setprio(0);
    __builtin_amdgcn_s_barrier();
  }
  __syncthreads();

  const int bb = m0 >> 11, s0q = m0 & 2047;
  if (n0 < 2048){
    #pragma unroll
    for (int mi = 0; mi < 8; ++mi){
      const int m = m0 + (2 * mi + wm) * 16 + r0;
      #pragma unroll
      for (int ni = 0; ni < 4; ++ni){
        const int n = n0 + (4 * ni + wn) * 16 + cl;
        const float bv = bias[n];
        const int part = n >> 10, rest = n & 1023;
        const int h = rest >> 6, d = rest & 63;
        #pragma unroll
        for (int jj = 0; jj < 4; ++jj){
          float v = acc[mi][ni][jj] + bv;
          if (part == 0) v *= 0.18033688011112042f;
          const int mm = m + jj;
          qkv[(size_t)part * 4194304 + (size_t)(((mm >> 11) * 16 + h) * 2048 + (mm & 2047)) * 64 + d] = f2bf(v);
        }
      }
    }
  } else {
    u16* tr = lds;                              // [4][64][258]
    const int h0 = (n0 - 2048) >> 6;
    #pragma unroll
    for (int mi = 0; mi < 8; ++mi){
      const int sl = (2 * mi + wm) * 16 + r0;
      #pragma unroll
      for (int ni = 0; ni < 4; ++ni){
        const float bv = bias[n0 + (4 * ni + wn) * 16 + cl];
        const int off = (ni * 64 + wn * 16 + cl) * 258 + sl;
        *(unsigned*)&tr[off]     = cvt_pk_bf16(acc[mi][ni][0] + bv, acc[mi][ni][1] + bv);
        *(unsigned*)&tr[off + 2] = cvt_pk_bf16(acc[mi][ni][2] + bv, acc[mi][ni][3] + bv);
      }
    }
    __syncthreads();
    u16* vt_base = qkv + (size_t)2 * 4194304;
    const int hh = tid >> 7, dd = (tid >> 1) & 63, hf = tid & 1;
    u16* dst = vt_base + ((size_t)((bb * 16 + h0 + hh) * 64 + dd)) * 2048 + s0q + hf * 128;
    const u16* srcr = &tr[(hh * 64 + dd) * 258 + hf * 128];
    #pragma unroll
    for (int k = 0; k < 16; ++k)
      *(uint4*)(dst + k * 8) = *(const uint4*)(srcr + k * 8);
  }
}

// ---------------- 128^2 GEMM (output projection) -------------------------------
__device__ __forceinline__ void stage_tile(const u16* __restrict__ G, u16* lds,
                                           int row0, int k0, int K, int tid){
  #pragma unroll
  for (int c = 0; c < 2; ++c){
    int e = c * 2048 + tid * 8;
    int row = e >> 5, col = e & 31;
    gl_lds16(G + (size_t)(row0 + row) * K + k0 + col, lds + c * 2048 + (tid >> 6) * 512);
  }
}

__global__ __launch_bounds__(256) void gemm_out(
    const u16* __restrict__ A, const u16* __restrict__ B,
    const float* __restrict__ bias, float* __restrict__ Cf,
    int M, int N, int K)
{
  __shared__ u16 smem[16384];
  u16* Ash = smem;
  u16* Bsh = smem + 8192;
  const int tid = threadIdx.x, lane = tid & 63;
  const int w = tid >> 6, wm = w >> 1, wn = w & 1;
  const int cl = lane & 15, g8 = (lane >> 4) * 8;

  const int bid = blockIdx.x;
  const int chunk = bid & 7, pos = bid >> 3;
  const int mt = (chunk >> 1) * 8 + pos / 4;
  const int nt = (chunk & 1) * 4 + pos % 4;
  const int n0 = nt * 128, m0 = mt * 128;

  facc acc[4][4];
  #pragma unroll
  for (int mi = 0; mi < 4; ++mi)
    #pragma unroll
    for (int ni = 0; ni < 4; ++ni)
      acc[mi][ni] = (facc){0.f, 0.f, 0.f, 0.f};

  const int NT = K >> 5;
  stage_tile(A, Ash, m0, 0, K, tid);
  stage_tile(B, Bsh, n0, 0, K, tid);
  __syncthreads();
  int cur = 0;
  for (int kt = 0; kt < NT; ++kt){
    if (kt + 1 < NT){
      stage_tile(A, Ash + (cur ^ 1) * 4096, m0, (kt + 1) << 5, K, tid);
      stage_tile(B, Bsh + (cur ^ 1) * 4096, n0, (kt + 1) << 5, K, tid);
    }
    const u16* As = Ash + cur * 4096; const u16* Bs = Bsh + cur * 4096;
    bfrag af[4], bfr[4];
    #pragma unroll
    for (int mi = 0; mi < 4; ++mi)
      af[mi] = *(const bfrag*)&As[(wm * 64 + mi * 16 + cl) * 32 + g8];
    #pragma unroll
    for (int ni = 0; ni < 4; ++ni)
      bfr[ni] = *(const bfrag*)&Bs[(wn * 64 + ni * 16 + cl) * 32 + g8];
    #pragma unroll
    for (int mi = 0; mi < 4; ++mi)
      #pragma unroll
      for (int ni = 0; ni < 4; ++ni)
        acc[mi][ni] = __builtin_amdgcn_mfma_f32_16x16x32_bf16(af[mi], bfr[ni], acc[mi][ni], 0, 0, 0);
    __syncthreads();
    cur ^= 1;
  }

  const int r0 = (lane >> 4) * 4;
  #pragma unroll
  for (int mi = 0; mi < 4; ++mi){
    const int mbase = m0 + wm * 64 + mi * 16 + r0;
    #pragma unroll
    for (int ni = 0; ni < 4; ++ni){
      const int n = n0 + wn * 64 + ni * 16 + cl;
      const float bv = bias[n];
      #pragma unroll
      for (int j = 0; j < 4; ++j)
        Cf[(size_t)(mbase + j) * N + n] = acc[mi][ni][j] + bv;
    }
  }
}

// ---------------- attention per-stripe body on SHARED loaded frags -------------
// NSUB: 32-wide j-subtiles to process (1 or 2). MASK: mask last sub (qj > il).
template<int NSUB, bool MASK>
__device__ __forceinline__ void stripe_body(
    const bfrag (&kf)[8], const bfrag (&vf)[8],
    int il, int hi, const bfrag (&bq)[4],
    f16x& o0, f16x& o1, float& m_s, float& l_s)
{
  f16x s[NSUB];
  #pragma unroll
  for (int sub = 0; sub < NSUB; ++sub)
    #pragma unroll
    for (int r = 0; r < 16; ++r) s[sub][r] = 0.f;
  __builtin_amdgcn_s_setprio(1);
  #pragma unroll
  for (int kt = 0; kt < 4; ++kt)
    #pragma unroll
    for (int sub = 0; sub < NSUB; ++sub)
      s[sub] = __builtin_amdgcn_mfma_f32_32x32x16_bf16(kf[sub * 4 + kt], bq[kt], s[sub], 0, 0, 0);
  __builtin_amdgcn_s_setprio(0);

  if (MASK){
    #pragma unroll
    for (int r = 0; r < 16; ++r){
      const int qj = (r & 3) + 8 * (r >> 2) + 4 * hi;
      if (qj > il) s[NSUB - 1][r] = -1e30f;
    }
  }

  float tmax = -1e30f;
  #pragma unroll
  for (int sub = 0; sub < NSUB; ++sub){
    float a[8];
    #pragma unroll
    for (int e = 0; e < 8; ++e) a[e] = fmaxf(s[sub][e], s[sub][e + 8]);
    #pragma unroll
    for (int e = 0; e < 4; ++e) a[e] = fmaxf(a[e], a[e + 4]);
    a[0] = fmaxf(fmaxf(a[0], a[2]), fmaxf(a[1], a[3]));
    tmax = fmaxf(tmax, a[0]);
  }
  {
    auto tt = __builtin_amdgcn_permlane32_swap(__float_as_uint(tmax),
                                               __float_as_uint(tmax), false, false);
    tmax = fmaxf(__uint_as_float(tt[0]), __uint_as_float(tt[1]));
  }
  if (__any(tmax - m_s > 8.0f)){                // defer-max (THR=8)
    const float nm = fmaxf(m_s, tmax);
    const float sc = __builtin_amdgcn_exp2f(m_s - nm);
    m_s = nm; l_s *= sc;
    #pragma unroll
    for (int r = 0; r < 16; ++r){
      const float scb = __shfl(sc, (r & 3) + 8 * (r >> 2) + 4 * hi, 64);
      o0[r] *= scb; o1[r] *= scb;
    }
  }

  float rsum = 0.f;
  #pragma unroll
  for (int sub = 0; sub < NSUB; ++sub){
    #pragma unroll
    for (int r = 0; r < 16; ++r)
      s[sub][r] = __builtin_amdgcn_exp2f(s[sub][r] - m_s);
    float a[8];
    #pragma unroll
    for (int e = 0; e < 8; ++e) a[e] = s[sub][e] + s[sub][e + 8];
    #pragma unroll
    for (int e = 0; e < 4; ++e) a[e] = a[e] + a[e + 4];
    rsum += (a[0] + a[2]) + (a[1] + a[3]);
  }
  {
    auto rr = __builtin_amdgcn_permlane32_swap(__float_as_uint(rsum),
                                               __float_as_uint(rsum), false, false);
    rsum = __uint_as_float(rr[0]) + __uint_as_float(rr[1]);
  }
  l_s += rsum;

  #pragma unroll
  for (int sub = 0; sub < NSUB; ++sub)
    #pragma unroll
    for (int half = 0; half < 2; ++half){
      const int q0 = 8 * half;
      unsigned a0 = cvt_pk_bf16(s[sub][q0],     s[sub][q0 + 1]);
      unsigned a1 = cvt_pk_bf16(s[sub][q0 + 2], s[sub][q0 + 3]);
      unsigned b0 = cvt_pk_bf16(s[sub][q0 + 4], s[sub][q0 + 5]);
      unsigned b1 = cvt_pk_bf16(s[sub][q0 + 6], s[sub][q0 + 7]);
      auto r0p = __builtin_amdgcn_permlane32_swap(a0, b0, false, false);
      auto r1p = __builtin_amdgcn_permlane32_swap(a1, b1, false, false);
      union { bfrag f; unsigned u[4]; } pa;
      pa.u[0] = r0p[0]; pa.u[1] = r1p[0]; pa.u[2] = r0p[1]; pa.u[3] = r1p[1];

      __builtin_amdgcn_s_setprio(1);
      o0 = __builtin_amdgcn_mfma_f32_32x32x16_bf16(pa.f, vf[sub * 4 + half * 2 + 0], o0, 0, 0, 0);
      o1 = __builtin_amdgcn_mfma_f32_32x32x16_bf16(pa.f, vf[sub * 4 + half * 2 + 1], o1, 0, 0, 0);
      __builtin_amdgcn_s_setprio(0);
    }
}

__device__ __forceinline__ void load_tile(
    bfrag (&kf)[8], bfrag (&vf)[8],
    const u16* __restrict__ Kt, const u16* __restrict__ VTh, int jt, int il, int hi)
{
  #pragma unroll
  for (int sub = 0; sub < 2; ++sub)
    #pragma unroll
    for (int half = 0; half < 2; ++half){
      const int jcol = jt * 64 + sub * 32 + half * 16 + hi * 8;
      vf[sub * 4 + half * 2 + 0] = *(const bfrag*)(VTh + (size_t)il * 2048 + jcol);
      vf[sub * 4 + half * 2 + 1] = *(const bfrag*)(VTh + (size_t)(32 + il) * 2048 + jcol);
    }
  #pragma unroll
  for (int sub = 0; sub < 2; ++sub)
    #pragma unroll
    for (int kt = 0; kt < 4; ++kt)
      kf[sub * 4 + kt] = *(const bfrag*)(Kt + (size_t)(sub * 32 + il) * 64 + kt * 16 + hi * 8);
}

// ---------------- swapped-role causal flash attention (64 rows/wave) -----------
// Block = 128 thr = 2 waves over the SAME 64 output rows (2 stripes of 32);
// wave w processes j-tiles of parity w; K/V frags loaded ONCE per tile and
// shared by both stripes (halves L2 traffic). 2-partial merge per stripe.
// __launch_bounds__(128,2): VGPR cap 256 -> no spill (R20/R15/R24 lessons).
__global__ __launch_bounds__(128, 2) void attn_kernel(
    const u16* __restrict__ qarr, const u16* __restrict__ karr,
    const u16* __restrict__ vtarr, u16* __restrict__ aout,
    const int* __restrict__ cmask)
{
  __shared__ float cO[64 * 64];                 // wave1 partial O (both stripes)
  __shared__ float cm0[64], cl0[64], cm1[64], cl1[64];
  const int tid = threadIdx.x, lane = tid & 63, w = tid >> 6;
  const int il = lane & 31, hi = lane >> 5;
  const int bh = blockIdx.x;                    // bh -> XCD (K/Q/VT L2-resident)
  const int bi = 31 - (int)blockIdx.y;          // 64-row block, heavy first
  const int i0 = bi * 64;
  const u16* Qh  = karr  + (size_t)bh * 131072; // output rows come from k-proj
  const u16* Kh  = qarr  + (size_t)bh * 131072; // keys are q-proj (pre-scaled)
  const u16* VTh = vtarr + (size_t)bh * 131072; // V transposed [d][s]
  const bool do_mask = (cmask[0] != 0);

  // Q B-frags for both stripes
  bfrag bqL[4], bqH[4];
  #pragma unroll
  for (int kt = 0; kt < 4; ++kt){
    bqL[kt] = *(const bfrag*)(Qh + (size_t)(i0 + il) * 64 + kt * 16 + hi * 8);
    bqH[kt] = *(const bfrag*)(Qh + (size_t)(i0 + 32 + il) * 64 + kt * 16 + hi * 8);
  }

  f16x o0L, o1L, o0H, o1H;
  #pragma unroll
  for (int r = 0; r < 16; ++r){ o0L[r] = 0.f; o1L[r] = 0.f; o0H[r] = 0.f; o1H[r] = 0.f; }
  float mL = -1e30f, lL = 0.f, mH = -1e30f, lH = 0.f;

  const int lim = do_mask ? bi : 32;            // full tiles: jt < lim

  bfrag kf[8], vf[8];
  for (int jt = w; jt < lim; jt += 2){          // parity split; shared loads
    load_tile(kf, vf, Kh + (size_t)jt * 4096, VTh, jt, il, hi);
    stripe_body<2, false>(kf, vf, il, hi, bqL, o0L, o1L, mL, lL);
    stripe_body<2, false>(kf, vf, il, hi, bqH, o0H, o1H, mH, lH);
  }

  if (do_mask && (bi & 1) == w){                // diagonal tile jt = bi, once
    load_tile(kf, vf, Kh + (size_t)bi * 4096, VTh, bi, il, hi);
    stripe_body<1, true>(kf, vf, il, hi, bqL, o0L, o1L, mL, lL);  // L: sub0 masked
    stripe_body<2, true>(kf, vf, il, hi, bqH, o0H, o1H, mH, lH);  // H: sub1 masked
  }

  // ---- merge the two j-parity partials, per stripe ----
  if (w == 1){
    #pragma unroll
    for (int r = 0; r < 16; ++r){
      const int row = (r & 3) + 8 * (r >> 2) + 4 * hi;
      cO[row * 64 + il]             = o0L[r];
      cO[row * 64 + il + 32]        = o1L[r];
      cO[(32 + row) * 64 + il]      = o0H[r];
      cO[(32 + row) * 64 + il + 32] = o1H[r];
    }
    cm1[il] = mL; cl1[il] = lL; cm1[32 + il] = mH; cl1[32 + il] = lH;
  } else {
    cm0[il] = mL; cl0[il] = lL; cm0[32 + il] = mH; cl0[32 + il] = lH;
  }
  __syncthreads();
  if (w == 0){
    const int bb = bh >> 4, h = bh & 15;
    #pragma unroll
    for (int p = 0; p < 2; ++p){
      #pragma unroll
      for (int r = 0; r < 16; ++r){
        const int rl = (r & 3) + 8 * (r >> 2) + 4 * hi;
        const int sr = p * 32 + rl;
        const float mA = cm0[sr], mB = cm1[sr];
        const float lA = cl0[sr], lB = cl1[sr];
        const float M  = fmaxf(mA, mB);
        const float eA = __builtin_amdgcn_exp2f(mA - M);
        const float eB = __builtin_amdgcn_exp2f(mB - M);
        const float inv = 1.0f / (lA * eA + lB * eB);
        const float ob0 = cO[sr * 64 + il], ob1 = cO[sr * 64 + il + 32];
        const float a0 = (p ? o0H[r] : o0L[r]) * eA + ob0 * eB;
        const float a1 = (p ? o1H[r] : o1L[r]) * eA + ob1 * eB;
        u16* dst = aout + (size_t)(bb * 2048 + i0 + sr) * 1024 + h * 64 + il;
        dst[0]  = f2bf(a0 * inv);
        dst[32] = f2bf(a1 * inv);
      }
    }
  }
}

// ---------------- launch ----------------
extern "C" void kernel_launch(void* const* d_in, const int* in_sizes, int n_in,
                              void* d_out, int out_size, void* d_ws, size_t ws_size,
                              hipStream_t stream)
{
  const float* x     = (const float*)d_in[0];
  const float* w_in  = (const float*)d_in[1];
  const float* b_in  = (const float*)d_in[2];
  const float* w_out = (const float*)d_in[3];
  const float* b_out = (const float*)d_in[4];
  const int*   cmask = (const int*)d_in[5];

  u16* ws     = (u16*)d_ws;
  u16* xb     = ws;                 // 4096x1024
  u16* winb   = ws + 4194304;       // 3072x1024
  u16* woutb  = ws + 7340032;       // 1024x1024
  u16* qs     = ws + 8388608;       // q,k: [2,16,2048,64]; VT: [2,16,64,2048]
  u16* attn_o = ws + 20971520;      // 4096x1024

  cvt3_kernel<<<8192, 256, 0, stream>>>(x, xb, 4194304,
                                        w_in, winb, 3145728,
                                        w_out, woutb);

  gemm8p_qkv<<<192, 512, 0, stream>>>(xb, winb, b_in, qs);

  attn_kernel<<<dim3(32, 32), 128, 0, stream>>>(qs, qs + 4194304, qs + 8388608, attn_o, cmask);

  gemm_out<<<256, 256, 0, stream>>>(attn_o, woutb, b_out, (float*)d_out,
                                    4096, 1024, 1024);
}